// Round 3
// baseline (152.713 us; speedup 1.0000x reference)
//
#include <hip/hip_runtime.h>
#include <hip/hip_bf16.h>

// Lorenz Euler integration: strictly serial recurrence over n_steps = T-1.
// One lane carries the (x,y,z) state in registers; writes each row of the
// [T,3] fp32 trajectory as it goes. Latency-bound (~8 dependent cycles/step).
//
// Algebraic restructure to shorten the dependent chain:
//   x' = x + DT*s*(y-x)     = (1-DT*s)*x + (DT*s)*y
//   y' = y + DT*(x*(r-z)-y) = (1-DT)*y + (DT*x)*(r-z)
//   z' = z + DT*(x*y-b*z)   = (1-DT*b)*z + DT*(x*y)

#define LORENZ_DT 0.01f

__global__ void lorenz_kernel(const float* __restrict__ sigma,
                              const float* __restrict__ rho,
                              const float* __restrict__ beta,
                              const float* __restrict__ stats,
                              float* __restrict__ out,
                              int n_t) {
    if (threadIdx.x != 0 || blockIdx.x != 0) return;

    const float s = sigma[0];
    const float r = rho[0];
    const float b = beta[0];

    const float dts = LORENZ_DT * s;        // DT*s
    const float cx  = 1.0f - dts;           // 1 - DT*s
    const float cy  = 1.0f - LORENZ_DT;     // 1 - DT
    const float cz  = 1.0f - LORENZ_DT * b; // 1 - DT*b

    float x = stats[0];
    float y = stats[1];
    float z = stats[2];

    // Row 0 = initial state.
    out[0] = x;
    out[1] = y;
    out[2] = z;

    const int n_steps = n_t - 1;
    float* p = out + 3;
    #pragma unroll 8
    for (int i = 0; i < n_steps; ++i) {
        const float rz  = r - z;             // independent of each other:
        const float dtx = LORENZ_DT * x;     //   these three issue in parallel
        const float xy  = x * y;
        const float nx = fmaf(dts, y, cx * x);
        const float ny = fmaf(dtx, rz, cy * y);
        const float nz = fmaf(LORENZ_DT, xy, cz * z);
        x = nx; y = ny; z = nz;
        p[0] = x;
        p[1] = y;
        p[2] = z;
        p += 3;
    }
}

extern "C" void kernel_launch(void* const* d_in, const int* in_sizes, int n_in,
                              void* d_out, int out_size, void* d_ws, size_t ws_size,
                              hipStream_t stream) {
    const float* t     = (const float*)d_in[0];  // unused beyond its length
    const float* sigma = (const float*)d_in[1];
    const float* rho   = (const float*)d_in[2];
    const float* beta  = (const float*)d_in[3];
    const float* stats = (const float*)d_in[4];
    float* out = (float*)d_out;
    (void)t; (void)d_ws; (void)ws_size; (void)out_size;

    const int n_t = in_sizes[0];  // 4000 time points -> 3999 steps

    lorenz_kernel<<<1, 64, 0, stream>>>(sigma, rho, beta, stats, out, n_t);
}